// Round 2
// baseline (2949.612 us; speedup 1.0000x reference)
//
#include <hip/hip_runtime.h>
#include <hip/hip_bf16.h>
#include <math.h>

#define B_  1024
#define T_  64
#define V_  1024
#define E_  512
#define M_  1024
#define L_  32
#define PE_ 512
#define PO_ 511
#define G3_ 1536
#define M2_ 2048

// LDS tile leading-dim pad: 68 floats keeps float4 alignment (68*4=272B ≡ 0 mod 16)
// and makes staging-write bank aliasing 2-way (free per m136).
#define LD_ 68

// ---------------------------------------------------------------- utilities
__global__ __launch_bounds__(256) void sincos_kernel(
    const float* __restrict__ x, float* __restrict__ c, float* __restrict__ s, int n) {
  int i = blockIdx.x * 256 + threadIdx.x;
  if (i < n) {
    float v = x[i];
    c[i] = cosf(v);
    s[i] = sinf(v);
  }
}

// ---------------------------------------------------------------- fp32 GEMM
// C[M,N] = A[M,K] * W[N,K]^T.  64x64 tile, BK=16, 256 threads, 4x4 microtile.
__global__ __launch_bounds__(256) void gemm_bt_f32(
    const float* __restrict__ A, const float* __restrict__ Wt,
    float* __restrict__ C, int Ndim, int K) {
  __shared__ float As[16 * LD_];
  __shared__ float Bs[16 * LD_];
  const int tid = threadIdx.x;
  const int m0 = blockIdx.y * 64, n0 = blockIdx.x * 64;
  const int tx = tid & 15, ty = tid >> 4;
  const int lr = tid >> 2;        // 0..63 staging row
  const int lk = (tid & 3) * 4;   // 0,4,8,12 staging k-offset
  float acc[4][4] = {};

  for (int k0 = 0; k0 < K; k0 += 16) {
    float4 a4 = *(const float4*)&A[(size_t)(m0 + lr) * K + k0 + lk];
    float4 b4 = *(const float4*)&Wt[(size_t)(n0 + lr) * K + k0 + lk];
    __syncthreads();
    As[(lk + 0) * LD_ + lr] = a4.x;
    As[(lk + 1) * LD_ + lr] = a4.y;
    As[(lk + 2) * LD_ + lr] = a4.z;
    As[(lk + 3) * LD_ + lr] = a4.w;
    Bs[(lk + 0) * LD_ + lr] = b4.x;
    Bs[(lk + 1) * LD_ + lr] = b4.y;
    Bs[(lk + 2) * LD_ + lr] = b4.z;
    Bs[(lk + 3) * LD_ + lr] = b4.w;
    __syncthreads();
#pragma unroll
    for (int kk = 0; kk < 16; kk++) {
      float4 av = *(const float4*)&As[kk * LD_ + ty * 4];
      float4 bv = *(const float4*)&Bs[kk * LD_ + tx * 4];
      float a[4] = {av.x, av.y, av.z, av.w};
      float b[4] = {bv.x, bv.y, bv.z, bv.w};
#pragma unroll
      for (int i = 0; i < 4; i++)
#pragma unroll
        for (int j = 0; j < 4; j++) acc[i][j] = fmaf(a[i], b[j], acc[i][j]);
    }
  }
#pragma unroll
  for (int i = 0; i < 4; i++) {
    float4 o = {acc[i][0], acc[i][1], acc[i][2], acc[i][3]};
    *(float4*)&C[(size_t)(m0 + ty * 4 + i) * Ndim + n0 + tx * 4] = o;
  }
}

// ---------------------------------------------------------------- GRU pointwise
__global__ __launch_bounds__(256) void gru_update(
    const int* __restrict__ tok, const float* __restrict__ eg,
    const float* __restrict__ gh, const float* __restrict__ b_ih,
    const float* __restrict__ b_hh, float* __restrict__ h, int t) {
  int idx = blockIdx.x * 256 + threadIdx.x;  // 0..B*E-1
  int b = idx >> 9;                          // /E_ (512)
  int e = idx & 511;
  int tk = tok[b * T_ + t];
  float ir = eg[(size_t)tk * G3_ + e] + b_ih[e];
  float iz = eg[(size_t)tk * G3_ + 512 + e] + b_ih[512 + e];
  float in_ = eg[(size_t)tk * G3_ + 1024 + e] + b_ih[1024 + e];
  float hr = gh[(size_t)b * G3_ + e] + b_hh[e];
  float hz = gh[(size_t)b * G3_ + 512 + e] + b_hh[512 + e];
  float hn = gh[(size_t)b * G3_ + 1024 + e] + b_hh[1024 + e];
  float r = 1.0f / (1.0f + expf(-(ir + hr)));
  float z = 1.0f / (1.0f + expf(-(iz + hz)));
  float n = tanhf(in_ + r * hn);
  float hv = h[idx];
  h[idx] = (1.0f - z) * n + z * hv;
}

// ---------------------------------------------------------------- MZI stack
__device__ inline void mzi_pair(float& x0r, float& x0i, float& x1r, float& x1i,
                                float ct, float st, float cp, float sp,
                                float cr, float sr) {
  float u11r = ct * (cp * cr - sp * sr), u11i = ct * (cp * sr + sp * cr);
  float u12r = -st * sp, u12i = st * cp;
  float u21r = -st * sr, u21i = st * cr;
  float u22r = ct;  // u22i = 0
  float n0r = u11r * x0r - u11i * x0i + u12r * x1r - u12i * x1i;
  float n0i = u11r * x0i + u11i * x0r + u12r * x1i + u12i * x1r;
  float n1r = u21r * x0r - u21i * x0i + u22r * x1r;
  float n1i = u21r * x0i + u21i * x0r + u22r * x1i;
  x0r = n0r; x0i = n0i; x1r = n1r; x1i = n1i;
}

__global__ __launch_bounds__(256) void quantum_core(
    const float* __restrict__ zc, const float* __restrict__ bc,
    const float* __restrict__ cph, const float* __restrict__ sph,
    const float* __restrict__ ce, const float* __restrict__ se,
    const float* __restrict__ cpe, const float* __restrict__ spe,
    const float* __restrict__ cre, const float* __restrict__ sre_,
    const float* __restrict__ co, const float* __restrict__ so,
    const float* __restrict__ cpo, const float* __restrict__ spo,
    const float* __restrict__ cro, const float* __restrict__ sro,
    float* __restrict__ pre_out, float* __restrict__ pim_out) {
  __shared__ float Sre[M_], Sim[M_];
  __shared__ float red[4];
  const int b = blockIdx.x, t = threadIdx.x;
  const int m0 = 4 * t;
  float xr[4], xi[4];
  {
    float4 zr = *(const float4*)&zc[(size_t)b * M2_ + m0];
    float4 zi = *(const float4*)&zc[(size_t)b * M2_ + M_ + m0];
    float4 br = *(const float4*)&bc[m0];
    float4 bi = *(const float4*)&bc[M_ + m0];
    xr[0] = zr.x + br.x; xr[1] = zr.y + br.y; xr[2] = zr.z + br.z; xr[3] = zr.w + br.w;
    xi[0] = zi.x + bi.x; xi[1] = zi.y + bi.y; xi[2] = zi.z + bi.z; xi[3] = zi.w + bi.w;
  }
#define NORMALIZE()                                                         \
  {                                                                         \
    float s = 0.0f;                                                         \
    for (int j = 0; j < 4; j++) s += xr[j] * xr[j] + xi[j] * xi[j];         \
    for (int off = 32; off; off >>= 1) s += __shfl_down(s, off, 64);        \
    if ((t & 63) == 0) red[t >> 6] = s;                                     \
    __syncthreads();                                                        \
    s = red[0] + red[1] + red[2] + red[3];                                  \
    float inv = 1.0f / sqrtf(s + 1e-8f);                                    \
    for (int j = 0; j < 4; j++) { xr[j] *= inv; xi[j] *= inv; }             \
  }

  NORMALIZE();

  for (int l = 0; l < L_; ++l) {
    {
      float4 c4 = *(const float4*)&cph[(size_t)l * M_ + m0];
      float4 s4 = *(const float4*)&sph[(size_t)l * M_ + m0];
      float cc[4] = {c4.x, c4.y, c4.z, c4.w};
      float ss[4] = {s4.x, s4.y, s4.z, s4.w};
#pragma unroll
      for (int j = 0; j < 4; j++) {
        float nr = xr[j] * cc[j] - xi[j] * ss[j];
        float ni = xr[j] * ss[j] + xi[j] * cc[j];
        xr[j] = nr; xi[j] = ni;
      }
    }
    {
      int p = l * PE_ + 2 * t;
      mzi_pair(xr[0], xi[0], xr[1], xi[1], ce[p], se[p], cpe[p], spe[p], cre[p], sre_[p]);
      mzi_pair(xr[2], xi[2], xr[3], xi[3], ce[p + 1], se[p + 1], cpe[p + 1], spe[p + 1],
               cre[p + 1], sre_[p + 1]);
    }
#pragma unroll
    for (int j = 0; j < 4; j++) { Sre[m0 + j] = xr[j]; Sim[m0 + j] = xi[j]; }
    __syncthreads();
    {
      int p = l * PO_ + 2 * t;
      float ar = Sre[m0 + 1], ai = Sim[m0 + 1];
      float br2 = Sre[m0 + 2], bi2 = Sim[m0 + 2];
      mzi_pair(ar, ai, br2, bi2, co[p], so[p], cpo[p], spo[p], cro[p], sro[p]);
      Sre[m0 + 1] = ar; Sim[m0 + 1] = ai; Sre[m0 + 2] = br2; Sim[m0 + 2] = bi2;
      if (t < 255) {
        float cr2 = Sre[m0 + 3], ci2 = Sim[m0 + 3];
        float dr = Sre[m0 + 4], di = Sim[m0 + 4];
        mzi_pair(cr2, ci2, dr, di, co[p + 1], so[p + 1], cpo[p + 1], spo[p + 1],
                 cro[p + 1], sro[p + 1]);
        Sre[m0 + 3] = cr2; Sim[m0 + 3] = ci2; Sre[m0 + 4] = dr; Sim[m0 + 4] = di;
      }
    }
    __syncthreads();
#pragma unroll
    for (int j = 0; j < 4; j++) { xr[j] = Sre[m0 + j]; xi[j] = Sim[m0 + j]; }
    NORMALIZE();
  }
#pragma unroll
  for (int j = 0; j < 4; j++) {
    pre_out[(size_t)b * M_ + m0 + j] = xr[j];
    pim_out[(size_t)b * M_ + m0 + j] = xi[j];
  }
#undef NORMALIZE
}

// ---------------------------------------------------------------- readout
// out[b,v] = log(|sum_m psi[b,m] * conj-free R[v,m]|^2 + 1e-12), fp32.
// 64x64 tile, BK=16, 4x4 microtile, re+im accumulated together.
__global__ __launch_bounds__(256) void readout_f32(
    const float* __restrict__ pre, const float* __restrict__ pim,
    const float* __restrict__ Rr, const float* __restrict__ Ri,
    float* __restrict__ out) {
  __shared__ float sAr[16 * LD_], sAi[16 * LD_], sBr[16 * LD_], sBi[16 * LD_];
  const int tid = threadIdx.x;
  const int b0 = blockIdx.y * 64, v0 = blockIdx.x * 64;
  const int tx = tid & 15, ty = tid >> 4;
  const int lr = tid >> 2;
  const int lk = (tid & 3) * 4;
  float are[4][4] = {}, aim[4][4] = {};

  for (int k0 = 0; k0 < M_; k0 += 16) {
    float4 ar4 = *(const float4*)&pre[(size_t)(b0 + lr) * M_ + k0 + lk];
    float4 ai4 = *(const float4*)&pim[(size_t)(b0 + lr) * M_ + k0 + lk];
    float4 br4 = *(const float4*)&Rr[(size_t)(v0 + lr) * M_ + k0 + lk];
    float4 bi4 = *(const float4*)&Ri[(size_t)(v0 + lr) * M_ + k0 + lk];
    __syncthreads();
    sAr[(lk + 0) * LD_ + lr] = ar4.x; sAr[(lk + 1) * LD_ + lr] = ar4.y;
    sAr[(lk + 2) * LD_ + lr] = ar4.z; sAr[(lk + 3) * LD_ + lr] = ar4.w;
    sAi[(lk + 0) * LD_ + lr] = ai4.x; sAi[(lk + 1) * LD_ + lr] = ai4.y;
    sAi[(lk + 2) * LD_ + lr] = ai4.z; sAi[(lk + 3) * LD_ + lr] = ai4.w;
    sBr[(lk + 0) * LD_ + lr] = br4.x; sBr[(lk + 1) * LD_ + lr] = br4.y;
    sBr[(lk + 2) * LD_ + lr] = br4.z; sBr[(lk + 3) * LD_ + lr] = br4.w;
    sBi[(lk + 0) * LD_ + lr] = bi4.x; sBi[(lk + 1) * LD_ + lr] = bi4.y;
    sBi[(lk + 2) * LD_ + lr] = bi4.z; sBi[(lk + 3) * LD_ + lr] = bi4.w;
    __syncthreads();
#pragma unroll
    for (int kk = 0; kk < 16; kk++) {
      float4 arv = *(const float4*)&sAr[kk * LD_ + ty * 4];
      float4 aiv = *(const float4*)&sAi[kk * LD_ + ty * 4];
      float4 brv = *(const float4*)&sBr[kk * LD_ + tx * 4];
      float4 biv = *(const float4*)&sBi[kk * LD_ + tx * 4];
      float ar[4] = {arv.x, arv.y, arv.z, arv.w};
      float ai[4] = {aiv.x, aiv.y, aiv.z, aiv.w};
      float br[4] = {brv.x, brv.y, brv.z, brv.w};
      float bi[4] = {biv.x, biv.y, biv.z, biv.w};
#pragma unroll
      for (int i = 0; i < 4; i++)
#pragma unroll
        for (int j = 0; j < 4; j++) {
          are[i][j] = fmaf(ar[i], br[j], are[i][j]);
          are[i][j] = fmaf(-ai[i], bi[j], are[i][j]);
          aim[i][j] = fmaf(ar[i], bi[j], aim[i][j]);
          aim[i][j] = fmaf(ai[i], br[j], aim[i][j]);
        }
    }
  }
#pragma unroll
  for (int i = 0; i < 4; i++) {
    float4 o;
    float* op = (float*)&o;
#pragma unroll
    for (int j = 0; j < 4; j++) {
      float re = are[i][j], im = aim[i][j];
      op[j] = logf(re * re + im * im + 1e-12f);
    }
    *(float4*)&out[(size_t)(b0 + ty * 4 + i) * V_ + v0 + tx * 4] = o;
  }
}

// ---------------------------------------------------------------- logsumexp
__global__ __launch_bounds__(256) void lse_kernel(float* __restrict__ out) {
  __shared__ float redm[4], reds[4];
  const int b = blockIdx.x, t = threadIdx.x;
  float4 v = *(float4*)&out[(size_t)b * V_ + 4 * t];
  float mx = fmaxf(fmaxf(v.x, v.y), fmaxf(v.z, v.w));
  for (int off = 32; off; off >>= 1) mx = fmaxf(mx, __shfl_down(mx, off, 64));
  if ((t & 63) == 0) redm[t >> 6] = mx;
  __syncthreads();
  mx = fmaxf(fmaxf(redm[0], redm[1]), fmaxf(redm[2], redm[3]));
  float s = expf(v.x - mx) + expf(v.y - mx) + expf(v.z - mx) + expf(v.w - mx);
  for (int off = 32; off; off >>= 1) s += __shfl_down(s, off, 64);
  if ((t & 63) == 0) reds[t >> 6] = s;
  __syncthreads();
  s = reds[0] + reds[1] + reds[2] + reds[3];
  float lse = mx + logf(s);
  v.x -= lse; v.y -= lse; v.z -= lse; v.w -= lse;
  *(float4*)&out[(size_t)b * V_ + 4 * t] = v;
}

// ---------------------------------------------------------------- launch
extern "C" void kernel_launch(void* const* d_in, const int* in_sizes, int n_in,
                              void* d_out, int out_size, void* d_ws, size_t ws_size,
                              hipStream_t stream) {
  const int*   tokens = (const int*)d_in[0];
  const float* W_ih_unused = (const float*)d_in[2];
  (void)W_ih_unused;
  const float* embed  = (const float*)d_in[1];
  const float* W_ih   = (const float*)d_in[2];
  const float* W_hh   = (const float*)d_in[3];
  const float* b_ih   = (const float*)d_in[4];
  const float* b_hh   = (const float*)d_in[5];
  const float* Wc     = (const float*)d_in[6];
  const float* bc     = (const float*)d_in[7];
  const float* phase  = (const float*)d_in[8];
  const float* theta_e = (const float*)d_in[9];
  const float* phi_e  = (const float*)d_in[10];
  const float* rho_e  = (const float*)d_in[11];
  const float* theta_o = (const float*)d_in[12];
  const float* phi_o  = (const float*)d_in[13];
  const float* rho_o  = (const float*)d_in[14];
  const float* R_real = (const float*)d_in[15];
  const float* R_imag = (const float*)d_in[16];
  float* out = (float*)d_out;

  char* w = (char*)d_ws;
  auto alloc = [&](size_t bytes) -> void* {
    void* p = (void*)w;
    w += (bytes + 255) & ~(size_t)255;
    return p;
  };
  float* h      = (float*)alloc((size_t)B_ * E_ * 4);
  float* eg     = (float*)alloc((size_t)V_ * G3_ * 4);
  float* gh     = (float*)alloc((size_t)B_ * G3_ * 4);
  float* zc     = (float*)alloc((size_t)B_ * M2_ * 4);
  float* pre_f  = (float*)alloc((size_t)B_ * M_ * 4);
  float* pim_f  = (float*)alloc((size_t)B_ * M_ * 4);
  float* cph = (float*)alloc((size_t)L_ * M_ * 4);
  float* sph = (float*)alloc((size_t)L_ * M_ * 4);
  float* ce  = (float*)alloc((size_t)L_ * PE_ * 4);
  float* se  = (float*)alloc((size_t)L_ * PE_ * 4);
  float* cpe = (float*)alloc((size_t)L_ * PE_ * 4);
  float* spe = (float*)alloc((size_t)L_ * PE_ * 4);
  float* cre = (float*)alloc((size_t)L_ * PE_ * 4);
  float* sre_ = (float*)alloc((size_t)L_ * PE_ * 4);
  float* co  = (float*)alloc((size_t)L_ * PO_ * 4);
  float* so  = (float*)alloc((size_t)L_ * PO_ * 4);
  float* cpo = (float*)alloc((size_t)L_ * PO_ * 4);
  float* spo = (float*)alloc((size_t)L_ * PO_ * 4);
  float* cro = (float*)alloc((size_t)L_ * PO_ * 4);
  float* sro = (float*)alloc((size_t)L_ * PO_ * 4);

  hipMemsetAsync(h, 0, (size_t)B_ * E_ * 4, stream);

  auto sc = [&](const float* x, float* c, float* s, int n) {
    sincos_kernel<<<(n + 255) / 256, 256, 0, stream>>>(x, c, s, n);
  };
  sc(phase, cph, sph, L_ * M_);
  sc(theta_e, ce, se, L_ * PE_);
  sc(phi_e, cpe, spe, L_ * PE_);
  sc(rho_e, cre, sre_, L_ * PE_);
  sc(theta_o, co, so, L_ * PO_);
  sc(phi_o, cpo, spo, L_ * PO_);
  sc(rho_o, cro, sro, L_ * PO_);

  // embed_gates = embed @ W_ih^T   (V x 3E), fp32
  {
    dim3 grid(G3_ / 64, V_ / 64);
    gemm_bt_f32<<<grid, 256, 0, stream>>>(embed, W_ih, eg, G3_, E_);
  }

  // GRU over T steps, fp32
  for (int t = 0; t < T_; ++t) {
    dim3 grid(G3_ / 64, B_ / 64);
    gemm_bt_f32<<<grid, 256, 0, stream>>>(h, W_hh, gh, G3_, E_);
    gru_update<<<(B_ * E_) / 256, 256, 0, stream>>>(tokens, eg, gh, b_ih, b_hh, h, t);
  }

  // zc = h @ Wc^T   (B x 2M), fp32
  {
    dim3 grid(M2_ / 64, B_ / 64);
    gemm_bt_f32<<<grid, 256, 0, stream>>>(h, Wc, zc, M2_, E_);
  }

  // MZI stack (all 32 layers fused), fp32 psi out
  quantum_core<<<B_, 256, 0, stream>>>(zc, bc, cph, sph, ce, se, cpe, spe, cre,
                                       sre_, co, so, cpo, spo, cro, sro,
                                       pre_f, pim_f);

  // readout: log |psi @ R^T|^2, fp32
  {
    dim3 grid(V_ / 64, B_ / 64);
    readout_f32<<<grid, 256, 0, stream>>>(pre_f, pim_f, R_real, R_imag, out);
  }

  // logsumexp normalization per row
  lse_kernel<<<B_, 256, 0, stream>>>(out);
}

// Round 3
// 1769.963 us; speedup vs baseline: 1.6665x; 1.6665x over previous
//
#include <hip/hip_runtime.h>
#include <hip/hip_bf16.h>
#include <math.h>

typedef __bf16 bf16_t;
typedef bf16_t bf16x8 __attribute__((ext_vector_type(8)));
typedef float  f32x4  __attribute__((ext_vector_type(4)));

#define B_  1024
#define T_  64
#define V_  1024
#define E_  512
#define M_  1024
#define L_  32
#define PE_ 512
#define PO_ 511
#define G3_ 1536
#define M2_ 2048

#define MFMA_BF16 __builtin_amdgcn_mfma_f32_16x16x32_bf16

// ---------------------------------------------------------------- utilities
__global__ __launch_bounds__(256) void sincos_kernel(
    const float* __restrict__ x, float* __restrict__ c, float* __restrict__ s, int n) {
  int i = blockIdx.x * 256 + threadIdx.x;
  if (i < n) {
    float v = x[i];
    c[i] = cosf(v);
    s[i] = sinf(v);
  }
}

// fp32 -> bf16 hi/lo split (x ~= hi + lo, ~16-bit mantissa)
__global__ __launch_bounds__(256) void split4_kernel(
    const float* __restrict__ src, bf16_t* __restrict__ hi,
    bf16_t* __restrict__ lo, int n) {
  int i4 = (blockIdx.x * 256 + threadIdx.x) * 4;
  if (i4 < n) {
    float4 v = *(const float4*)&src[i4];
    float vv[4] = {v.x, v.y, v.z, v.w};
#pragma unroll
    for (int j = 0; j < 4; j++) {
      bf16_t h = (bf16_t)vv[j];
      hi[i4 + j] = h;
      lo[i4 + j] = (bf16_t)(vv[j] - (float)h);
    }
  }
}

// W_hh (1536x512) -> Wp[c][j][k]: c = e-chunk (8), j = gate*64 + e_local (192)
__global__ __launch_bounds__(256) void permute_whh_split(
    const float* __restrict__ W_hh, bf16_t* __restrict__ Wp_hi,
    bf16_t* __restrict__ Wp_lo) {
  int rowid = blockIdx.x;  // 0..1535 = c*192 + j
  int c = rowid / 192, j = rowid % 192;
  int g = j >> 6, e = c * 64 + (j & 63);
  const float* src = &W_hh[(size_t)(g * 512 + e) * 512];
  bf16_t* dh = &Wp_hi[(size_t)rowid * 512];
  bf16_t* dl = &Wp_lo[(size_t)rowid * 512];
  for (int k = threadIdx.x; k < 512; k += 256) {
    float v = src[k];
    bf16_t h = (bf16_t)v;
    dh[k] = h;
    dl[k] = (bf16_t)(v - (float)h);
  }
}

// ---------------------------------------------------------------- generic split GEMM
// C[M,N] f32 = (Ah+Al)[M,K] @ (Bh+Bl)[N,K]^T via 3-product bf16 MFMA.
// 64x64 tile, 4 waves 2x2, wave does 32x32 = 2x2 MFMA tiles.
__global__ __launch_bounds__(256) void gemm_bt_mfma_split(
    const bf16_t* __restrict__ Ah, const bf16_t* __restrict__ Al,
    const bf16_t* __restrict__ Bh, const bf16_t* __restrict__ Bl,
    float* __restrict__ C, int Ndim, int K) {
  __shared__ bf16_t sAh[64 * 32], sAl[64 * 32], sBh[64 * 32], sBl[64 * 32];
  const int tid = threadIdx.x;
  const int m0 = blockIdx.y * 64, n0 = blockIdx.x * 64;
  const int wave = tid >> 6, lane = tid & 63;
  const int wr = wave >> 1, wc = wave & 1;
  const int quad = lane >> 4, l16 = lane & 15;
  f32x4 acc[2][2] = {};
  const int srow = tid >> 2, sk = (tid & 3) * 8;

  for (int k0 = 0; k0 < K; k0 += 32) {
    bf16x8 ah = *(const bf16x8*)&Ah[(size_t)(m0 + srow) * K + k0 + sk];
    bf16x8 al = *(const bf16x8*)&Al[(size_t)(m0 + srow) * K + k0 + sk];
    bf16x8 bh = *(const bf16x8*)&Bh[(size_t)(n0 + srow) * K + k0 + sk];
    bf16x8 bl = *(const bf16x8*)&Bl[(size_t)(n0 + srow) * K + k0 + sk];
    __syncthreads();
    *(bf16x8*)&sAh[srow * 32 + sk] = ah;
    *(bf16x8*)&sAl[srow * 32 + sk] = al;
    *(bf16x8*)&sBh[srow * 32 + sk] = bh;
    *(bf16x8*)&sBl[srow * 32 + sk] = bl;
    __syncthreads();
    bf16x8 fAh[2], fAl[2], fBh[2], fBl[2];
#pragma unroll
    for (int i = 0; i < 2; i++) {
      fAh[i] = *(const bf16x8*)&sAh[(wr * 32 + i * 16 + l16) * 32 + quad * 8];
      fAl[i] = *(const bf16x8*)&sAl[(wr * 32 + i * 16 + l16) * 32 + quad * 8];
      fBh[i] = *(const bf16x8*)&sBh[(wc * 32 + i * 16 + l16) * 32 + quad * 8];
      fBl[i] = *(const bf16x8*)&sBl[(wc * 32 + i * 16 + l16) * 32 + quad * 8];
    }
#pragma unroll
    for (int i = 0; i < 2; i++)
#pragma unroll
      for (int j = 0; j < 2; j++) {
        acc[i][j] = MFMA_BF16(fAh[i], fBh[j], acc[i][j], 0, 0, 0);
        acc[i][j] = MFMA_BF16(fAh[i], fBl[j], acc[i][j], 0, 0, 0);
        acc[i][j] = MFMA_BF16(fAl[i], fBh[j], acc[i][j], 0, 0, 0);
      }
  }
#pragma unroll
  for (int i = 0; i < 2; i++)
#pragma unroll
    for (int j = 0; j < 2; j++)
#pragma unroll
      for (int r = 0; r < 4; r++) {
        int row = wr * 32 + i * 16 + quad * 4 + r;
        int col = wc * 32 + j * 16 + l16;
        C[(size_t)(m0 + row) * Ndim + n0 + col] = acc[i][j][r];
      }
}

// ---------------------------------------------------------------- fused GRU step
// Block (c, mt): computes gh tile [64 rows x 192 cols] = h @ Wp[c]^T, then the
// full GRU gate update for those (b, e) pairs. One launch per timestep.
__global__ __launch_bounds__(256) void gru_step(
    const bf16_t* __restrict__ hi_in, const bf16_t* __restrict__ lo_in,
    const bf16_t* __restrict__ Wp_hi, const bf16_t* __restrict__ Wp_lo,
    const int* __restrict__ tok, const float* __restrict__ eg,
    const float* __restrict__ b_ih, const float* __restrict__ b_hh,
    bf16_t* __restrict__ hi_out, bf16_t* __restrict__ lo_out, int t) {
  __shared__ bf16_t sAh[64 * 32], sAl[64 * 32];
  __shared__ bf16_t sBh[192 * 32], sBl[192 * 32];
  __shared__ float sC[64 * 200];  // pad 192->200 to break conflicts
  const int tid = threadIdx.x;
  const int c = blockIdx.x, m0 = blockIdx.y * 64;
  const int wave = tid >> 6, lane = tid & 63;
  const int quad = lane >> 4, l16 = lane & 15;
  f32x4 acc[4][3] = {};
  const int srow = tid >> 2, sk = (tid & 3) * 8;

  for (int k0 = 0; k0 < 512; k0 += 32) {
    bf16x8 ah = *(const bf16x8*)&hi_in[(size_t)(m0 + srow) * 512 + k0 + sk];
    bf16x8 al = *(const bf16x8*)&lo_in[(size_t)(m0 + srow) * 512 + k0 + sk];
    bf16x8 bh0 = *(const bf16x8*)&Wp_hi[(size_t)(c * 192 + srow) * 512 + k0 + sk];
    bf16x8 bh1 = *(const bf16x8*)&Wp_hi[(size_t)(c * 192 + srow + 64) * 512 + k0 + sk];
    bf16x8 bh2 = *(const bf16x8*)&Wp_hi[(size_t)(c * 192 + srow + 128) * 512 + k0 + sk];
    bf16x8 bl0 = *(const bf16x8*)&Wp_lo[(size_t)(c * 192 + srow) * 512 + k0 + sk];
    bf16x8 bl1 = *(const bf16x8*)&Wp_lo[(size_t)(c * 192 + srow + 64) * 512 + k0 + sk];
    bf16x8 bl2 = *(const bf16x8*)&Wp_lo[(size_t)(c * 192 + srow + 128) * 512 + k0 + sk];
    __syncthreads();
    *(bf16x8*)&sAh[srow * 32 + sk] = ah;
    *(bf16x8*)&sAl[srow * 32 + sk] = al;
    *(bf16x8*)&sBh[srow * 32 + sk] = bh0;
    *(bf16x8*)&sBh[(srow + 64) * 32 + sk] = bh1;
    *(bf16x8*)&sBh[(srow + 128) * 32 + sk] = bh2;
    *(bf16x8*)&sBl[srow * 32 + sk] = bl0;
    *(bf16x8*)&sBl[(srow + 64) * 32 + sk] = bl1;
    *(bf16x8*)&sBl[(srow + 128) * 32 + sk] = bl2;
    __syncthreads();
    bf16x8 fAh[4], fAl[4], fBh[3], fBl[3];
#pragma unroll
    for (int i = 0; i < 4; i++) {
      fAh[i] = *(const bf16x8*)&sAh[(i * 16 + l16) * 32 + quad * 8];
      fAl[i] = *(const bf16x8*)&sAl[(i * 16 + l16) * 32 + quad * 8];
    }
#pragma unroll
    for (int j = 0; j < 3; j++) {
      int n = wave * 48 + j * 16 + l16;
      fBh[j] = *(const bf16x8*)&sBh[n * 32 + quad * 8];
      fBl[j] = *(const bf16x8*)&sBl[n * 32 + quad * 8];
    }
#pragma unroll
    for (int i = 0; i < 4; i++)
#pragma unroll
      for (int j = 0; j < 3; j++) {
        acc[i][j] = MFMA_BF16(fAh[i], fBh[j], acc[i][j], 0, 0, 0);
        acc[i][j] = MFMA_BF16(fAh[i], fBl[j], acc[i][j], 0, 0, 0);
        acc[i][j] = MFMA_BF16(fAl[i], fBh[j], acc[i][j], 0, 0, 0);
      }
  }
  // scatter acc -> sC (cross-wave gate gather needs LDS round-trip)
  __syncthreads();
#pragma unroll
  for (int i = 0; i < 4; i++)
#pragma unroll
    for (int j = 0; j < 3; j++)
#pragma unroll
      for (int r = 0; r < 4; r++)
        sC[(i * 16 + quad * 4 + r) * 200 + wave * 48 + j * 16 + l16] = acc[i][j][r];
  __syncthreads();
  // gate update: 16 (row, e) pairs per thread
#pragma unroll 4
  for (int u = 0; u < 16; u++) {
    int flat = u * 256 + tid;
    int row = flat >> 6, el = flat & 63;
    int b = m0 + row;
    int eg_col = c * 64 + el;
    float cr = sC[row * 200 + el];
    float cz = sC[row * 200 + 64 + el];
    float cn = sC[row * 200 + 128 + el];
    int tk = tok[b * T_ + t];
    float ir = eg[(size_t)tk * G3_ + eg_col] + b_ih[eg_col];
    float iz = eg[(size_t)tk * G3_ + 512 + eg_col] + b_ih[512 + eg_col];
    float in_ = eg[(size_t)tk * G3_ + 1024 + eg_col] + b_ih[1024 + eg_col];
    float hr = cr + b_hh[eg_col];
    float hz = cz + b_hh[512 + eg_col];
    float hn = cn + b_hh[1024 + eg_col];
    float r = 1.0f / (1.0f + __expf(-(ir + hr)));
    float z = 1.0f / (1.0f + __expf(-(iz + hz)));
    float targ = in_ + r * hn;
    targ = fminf(fmaxf(targ, -15.0f), 15.0f);
    float e2 = __expf(2.0f * targ);
    float n = (e2 - 1.0f) / (e2 + 1.0f);
    size_t hidx = (size_t)b * 512 + eg_col;
    float hv = (float)hi_in[hidx] + (float)lo_in[hidx];
    float hnew = (1.0f - z) * n + z * hv;
    bf16_t hh = (bf16_t)hnew;
    hi_out[hidx] = hh;
    lo_out[hidx] = (bf16_t)(hnew - (float)hh);
  }
}

// ---------------------------------------------------------------- MZI stack
__device__ inline void mzi_pair(float& x0r, float& x0i, float& x1r, float& x1i,
                                float ct, float st, float cp, float sp,
                                float cr, float sr) {
  float u11r = ct * (cp * cr - sp * sr), u11i = ct * (cp * sr + sp * cr);
  float u12r = -st * sp, u12i = st * cp;
  float u21r = -st * sr, u21i = st * cr;
  float u22r = ct;  // u22i = 0
  float n0r = u11r * x0r - u11i * x0i + u12r * x1r - u12i * x1i;
  float n0i = u11r * x0i + u11i * x0r + u12r * x1i + u12i * x1r;
  float n1r = u21r * x0r - u21i * x0i + u22r * x1r;
  float n1i = u21r * x0i + u21i * x0r + u22r * x1i;
  x0r = n0r; x0i = n0i; x1r = n1r; x1i = n1i;
}

__global__ __launch_bounds__(256) void quantum_core(
    const float* __restrict__ zc, const float* __restrict__ bc,
    const float* __restrict__ cph, const float* __restrict__ sph,
    const float* __restrict__ ce, const float* __restrict__ se,
    const float* __restrict__ cpe, const float* __restrict__ spe,
    const float* __restrict__ cre, const float* __restrict__ sre_,
    const float* __restrict__ co, const float* __restrict__ so,
    const float* __restrict__ cpo, const float* __restrict__ spo,
    const float* __restrict__ cro, const float* __restrict__ sro,
    bf16_t* __restrict__ prh, bf16_t* __restrict__ prl,
    bf16_t* __restrict__ pih, bf16_t* __restrict__ pil) {
  __shared__ float Sre[M_], Sim[M_];
  __shared__ float red[4];
  const int b = blockIdx.x, t = threadIdx.x;
  const int m0 = 4 * t;
  float xr[4], xi[4];
  {
    float4 zr = *(const float4*)&zc[(size_t)b * M2_ + m0];
    float4 zi = *(const float4*)&zc[(size_t)b * M2_ + M_ + m0];
    float4 br = *(const float4*)&bc[m0];
    float4 bi = *(const float4*)&bc[M_ + m0];
    xr[0] = zr.x + br.x; xr[1] = zr.y + br.y; xr[2] = zr.z + br.z; xr[3] = zr.w + br.w;
    xi[0] = zi.x + bi.x; xi[1] = zi.y + bi.y; xi[2] = zi.z + bi.z; xi[3] = zi.w + bi.w;
  }
#define NORMALIZE()                                                         \
  {                                                                         \
    float s = 0.0f;                                                         \
    for (int j = 0; j < 4; j++) s += xr[j] * xr[j] + xi[j] * xi[j];         \
    for (int off = 32; off; off >>= 1) s += __shfl_down(s, off, 64);        \
    if ((t & 63) == 0) red[t >> 6] = s;                                     \
    __syncthreads();                                                        \
    s = red[0] + red[1] + red[2] + red[3];                                  \
    float inv = 1.0f / sqrtf(s + 1e-8f);                                    \
    for (int j = 0; j < 4; j++) { xr[j] *= inv; xi[j] *= inv; }             \
  }

  NORMALIZE();

  for (int l = 0; l < L_; ++l) {
    {
      float4 c4 = *(const float4*)&cph[(size_t)l * M_ + m0];
      float4 s4 = *(const float4*)&sph[(size_t)l * M_ + m0];
      float cc[4] = {c4.x, c4.y, c4.z, c4.w};
      float ss[4] = {s4.x, s4.y, s4.z, s4.w};
#pragma unroll
      for (int j = 0; j < 4; j++) {
        float nr = xr[j] * cc[j] - xi[j] * ss[j];
        float ni = xr[j] * ss[j] + xi[j] * cc[j];
        xr[j] = nr; xi[j] = ni;
      }
    }
    {
      int p = l * PE_ + 2 * t;
      mzi_pair(xr[0], xi[0], xr[1], xi[1], ce[p], se[p], cpe[p], spe[p], cre[p], sre_[p]);
      mzi_pair(xr[2], xi[2], xr[3], xi[3], ce[p + 1], se[p + 1], cpe[p + 1], spe[p + 1],
               cre[p + 1], sre_[p + 1]);
    }
#pragma unroll
    for (int j = 0; j < 4; j++) { Sre[m0 + j] = xr[j]; Sim[m0 + j] = xi[j]; }
    __syncthreads();
    {
      int p = l * PO_ + 2 * t;
      float ar = Sre[m0 + 1], ai = Sim[m0 + 1];
      float br2 = Sre[m0 + 2], bi2 = Sim[m0 + 2];
      mzi_pair(ar, ai, br2, bi2, co[p], so[p], cpo[p], spo[p], cro[p], sro[p]);
      Sre[m0 + 1] = ar; Sim[m0 + 1] = ai; Sre[m0 + 2] = br2; Sim[m0 + 2] = bi2;
      if (t < 255) {
        float cr2 = Sre[m0 + 3], ci2 = Sim[m0 + 3];
        float dr = Sre[m0 + 4], di = Sim[m0 + 4];
        mzi_pair(cr2, ci2, dr, di, co[p + 1], so[p + 1], cpo[p + 1], spo[p + 1],
                 cro[p + 1], sro[p + 1]);
        Sre[m0 + 3] = cr2; Sim[m0 + 3] = ci2; Sre[m0 + 4] = dr; Sim[m0 + 4] = di;
      }
    }
    __syncthreads();
#pragma unroll
    for (int j = 0; j < 4; j++) { xr[j] = Sre[m0 + j]; xi[j] = Sim[m0 + j]; }
    NORMALIZE();
  }
#pragma unroll
  for (int j = 0; j < 4; j++) {
    size_t idx = (size_t)b * M_ + m0 + j;
    bf16_t h;
    h = (bf16_t)xr[j]; prh[idx] = h; prl[idx] = (bf16_t)(xr[j] - (float)h);
    h = (bf16_t)xi[j]; pih[idx] = h; pil[idx] = (bf16_t)(xi[j] - (float)h);
  }
#undef NORMALIZE
}

// ---------------------------------------------------------------- readout
// out[b,v] = log(|psi . R_row|^2 + 1e-12) via split-bf16 complex MFMA.
// aP = ar*br, aQ = ai*bi (separate accumulators; re = aP - aQ), aI = ar*bi + ai*br.
__global__ __launch_bounds__(256) void readout_mfma(
    const bf16_t* __restrict__ Arh, const bf16_t* __restrict__ Arl,
    const bf16_t* __restrict__ Aih, const bf16_t* __restrict__ Ail,
    const bf16_t* __restrict__ Brh, const bf16_t* __restrict__ Brl,
    const bf16_t* __restrict__ Bih, const bf16_t* __restrict__ Bil,
    float* __restrict__ out) {
  __shared__ bf16_t sArh[64 * 32], sArl[64 * 32], sAih[64 * 32], sAil[64 * 32];
  __shared__ bf16_t sBrh[64 * 32], sBrl[64 * 32], sBih[64 * 32], sBil[64 * 32];
  const int tid = threadIdx.x;
  const int b0 = blockIdx.y * 64, v0 = blockIdx.x * 64;
  const int wave = tid >> 6, lane = tid & 63;
  const int wr = wave >> 1, wc = wave & 1;
  const int quad = lane >> 4, l16 = lane & 15;
  f32x4 aP[2][2] = {}, aQ[2][2] = {}, aI[2][2] = {};
  const int srow = tid >> 2, sk = (tid & 3) * 8;

  for (int k0 = 0; k0 < M_; k0 += 32) {
    size_t aoff = (size_t)(b0 + srow) * M_ + k0 + sk;
    size_t boff = (size_t)(v0 + srow) * M_ + k0 + sk;
    bf16x8 v0r = *(const bf16x8*)&Arh[aoff];
    bf16x8 v1r = *(const bf16x8*)&Arl[aoff];
    bf16x8 v2r = *(const bf16x8*)&Aih[aoff];
    bf16x8 v3r = *(const bf16x8*)&Ail[aoff];
    bf16x8 v4r = *(const bf16x8*)&Brh[boff];
    bf16x8 v5r = *(const bf16x8*)&Brl[boff];
    bf16x8 v6r = *(const bf16x8*)&Bih[boff];
    bf16x8 v7r = *(const bf16x8*)&Bil[boff];
    __syncthreads();
    *(bf16x8*)&sArh[srow * 32 + sk] = v0r;
    *(bf16x8*)&sArl[srow * 32 + sk] = v1r;
    *(bf16x8*)&sAih[srow * 32 + sk] = v2r;
    *(bf16x8*)&sAil[srow * 32 + sk] = v3r;
    *(bf16x8*)&sBrh[srow * 32 + sk] = v4r;
    *(bf16x8*)&sBrl[srow * 32 + sk] = v5r;
    *(bf16x8*)&sBih[srow * 32 + sk] = v6r;
    *(bf16x8*)&sBil[srow * 32 + sk] = v7r;
    __syncthreads();
    bf16x8 fArh[2], fArl[2], fAih[2], fAil[2], fBrh[2], fBrl[2], fBih[2], fBil[2];
#pragma unroll
    for (int i = 0; i < 2; i++) {
      int ra = (wr * 32 + i * 16 + l16) * 32 + quad * 8;
      int rb = (wc * 32 + i * 16 + l16) * 32 + quad * 8;
      fArh[i] = *(const bf16x8*)&sArh[ra];
      fArl[i] = *(const bf16x8*)&sArl[ra];
      fAih[i] = *(const bf16x8*)&sAih[ra];
      fAil[i] = *(const bf16x8*)&sAil[ra];
      fBrh[i] = *(const bf16x8*)&sBrh[rb];
      fBrl[i] = *(const bf16x8*)&sBrl[rb];
      fBih[i] = *(const bf16x8*)&sBih[rb];
      fBil[i] = *(const bf16x8*)&sBil[rb];
    }
#pragma unroll
    for (int i = 0; i < 2; i++)
#pragma unroll
      for (int j = 0; j < 2; j++) {
        aP[i][j] = MFMA_BF16(fArh[i], fBrh[j], aP[i][j], 0, 0, 0);
        aP[i][j] = MFMA_BF16(fArh[i], fBrl[j], aP[i][j], 0, 0, 0);
        aP[i][j] = MFMA_BF16(fArl[i], fBrh[j], aP[i][j], 0, 0, 0);
        aQ[i][j] = MFMA_BF16(fAih[i], fBih[j], aQ[i][j], 0, 0, 0);
        aQ[i][j] = MFMA_BF16(fAih[i], fBil[j], aQ[i][j], 0, 0, 0);
        aQ[i][j] = MFMA_BF16(fAil[i], fBih[j], aQ[i][j], 0, 0, 0);
        aI[i][j] = MFMA_BF16(fArh[i], fBih[j], aI[i][j], 0, 0, 0);
        aI[i][j] = MFMA_BF16(fArh[i], fBil[j], aI[i][j], 0, 0, 0);
        aI[i][j] = MFMA_BF16(fArl[i], fBih[j], aI[i][j], 0, 0, 0);
        aI[i][j] = MFMA_BF16(fAih[i], fBrh[j], aI[i][j], 0, 0, 0);
        aI[i][j] = MFMA_BF16(fAih[i], fBrl[j], aI[i][j], 0, 0, 0);
        aI[i][j] = MFMA_BF16(fAil[i], fBrh[j], aI[i][j], 0, 0, 0);
      }
  }
#pragma unroll
  for (int i = 0; i < 2; i++)
#pragma unroll
    for (int j = 0; j < 2; j++)
#pragma unroll
      for (int r = 0; r < 4; r++) {
        int row = wr * 32 + i * 16 + quad * 4 + r;
        int col = wc * 32 + j * 16 + l16;
        float re = aP[i][j][r] - aQ[i][j][r];
        float im = aI[i][j][r];
        out[(size_t)(b0 + row) * V_ + v0 + col] = logf(re * re + im * im + 1e-12f);
      }
}

// ---------------------------------------------------------------- logsumexp
__global__ __launch_bounds__(256) void lse_kernel(float* __restrict__ out) {
  __shared__ float redm[4], reds[4];
  const int b = blockIdx.x, t = threadIdx.x;
  float4 v = *(float4*)&out[(size_t)b * V_ + 4 * t];
  float mx = fmaxf(fmaxf(v.x, v.y), fmaxf(v.z, v.w));
  for (int off = 32; off; off >>= 1) mx = fmaxf(mx, __shfl_down(mx, off, 64));
  if ((t & 63) == 0) redm[t >> 6] = mx;
  __syncthreads();
  mx = fmaxf(fmaxf(redm[0], redm[1]), fmaxf(redm[2], redm[3]));
  float s = expf(v.x - mx) + expf(v.y - mx) + expf(v.z - mx) + expf(v.w - mx);
  for (int off = 32; off; off >>= 1) s += __shfl_down(s, off, 64);
  if ((t & 63) == 0) reds[t >> 6] = s;
  __syncthreads();
  s = reds[0] + reds[1] + reds[2] + reds[3];
  float lse = mx + logf(s);
  v.x -= lse; v.y -= lse; v.z -= lse; v.w -= lse;
  *(float4*)&out[(size_t)b * V_ + 4 * t] = v;
}

// ---------------------------------------------------------------- launch
extern "C" void kernel_launch(void* const* d_in, const int* in_sizes, int n_in,
                              void* d_out, int out_size, void* d_ws, size_t ws_size,
                              hipStream_t stream) {
  const int*   tokens = (const int*)d_in[0];
  const float* embed  = (const float*)d_in[1];
  const float* W_ih   = (const float*)d_in[2];
  const float* W_hh   = (const float*)d_in[3];
  const float* b_ih   = (const float*)d_in[4];
  const float* b_hh   = (const float*)d_in[5];
  const float* Wc     = (const float*)d_in[6];
  const float* bc     = (const float*)d_in[7];
  const float* phase  = (const float*)d_in[8];
  const float* theta_e = (const float*)d_in[9];
  const float* phi_e  = (const float*)d_in[10];
  const float* rho_e  = (const float*)d_in[11];
  const float* theta_o = (const float*)d_in[12];
  const float* phi_o  = (const float*)d_in[13];
  const float* rho_o  = (const float*)d_in[14];
  const float* R_real = (const float*)d_in[15];
  const float* R_imag = (const float*)d_in[16];
  float* out = (float*)d_out;

  char* w = (char*)d_ws;
  auto alloc = [&](size_t bytes) -> void* {
    void* p = (void*)w;
    w += (bytes + 255) & ~(size_t)255;
    return p;
  };
  // region0: weight splits; later ALIASED by psi hi/lo arrays (all dead by then)
  char* region0 = w;
  bf16_t* emb_hi = (bf16_t*)alloc((size_t)V_ * E_ * 2);    // 0.5 MB... (V*E=524288 el, 1 MB)
  bf16_t* emb_lo = (bf16_t*)alloc((size_t)V_ * E_ * 2);
  bf16_t* wih_hi = (bf16_t*)alloc((size_t)G3_ * E_ * 2);
  bf16_t* wih_lo = (bf16_t*)alloc((size_t)G3_ * E_ * 2);
  bf16_t* wc_hi  = (bf16_t*)alloc((size_t)M2_ * E_ * 2);
  bf16_t* wc_lo  = (bf16_t*)alloc((size_t)M2_ * E_ * 2);
  // region1: eg + Wp; later ALIASED by zc
  char* region1 = w;
  float*  eg     = (float*)alloc((size_t)V_ * G3_ * 4);
  bf16_t* Wp_hi  = (bf16_t*)alloc((size_t)G3_ * E_ * 2);
  bf16_t* Wp_lo  = (bf16_t*)alloc((size_t)G3_ * E_ * 2);
  // persistent regions
  bf16_t* h0_hi = (bf16_t*)alloc((size_t)B_ * E_ * 2);
  bf16_t* h0_lo = (bf16_t*)alloc((size_t)B_ * E_ * 2);
  bf16_t* h1_hi = (bf16_t*)alloc((size_t)B_ * E_ * 2);
  bf16_t* h1_lo = (bf16_t*)alloc((size_t)B_ * E_ * 2);
  bf16_t* rr_hi = (bf16_t*)alloc((size_t)V_ * M_ * 2);
  bf16_t* rr_lo = (bf16_t*)alloc((size_t)V_ * M_ * 2);
  bf16_t* ri_hi = (bf16_t*)alloc((size_t)V_ * M_ * 2);
  bf16_t* ri_lo = (bf16_t*)alloc((size_t)V_ * M_ * 2);
  float* cph = (float*)alloc((size_t)L_ * M_ * 4);
  float* sph = (float*)alloc((size_t)L_ * M_ * 4);
  float* ce  = (float*)alloc((size_t)L_ * PE_ * 4);
  float* se  = (float*)alloc((size_t)L_ * PE_ * 4);
  float* cpe = (float*)alloc((size_t)L_ * PE_ * 4);
  float* spe = (float*)alloc((size_t)L_ * PE_ * 4);
  float* cre = (float*)alloc((size_t)L_ * PE_ * 4);
  float* sre_ = (float*)alloc((size_t)L_ * PE_ * 4);
  float* co  = (float*)alloc((size_t)L_ * PO_ * 4);
  float* so  = (float*)alloc((size_t)L_ * PO_ * 4);
  float* cpo = (float*)alloc((size_t)L_ * PO_ * 4);
  float* spo = (float*)alloc((size_t)L_ * PO_ * 4);
  float* cro = (float*)alloc((size_t)L_ * PO_ * 4);
  float* sro = (float*)alloc((size_t)L_ * PO_ * 4);

  // aliases (activated after their underlying data is dead)
  float*  zc  = (float*)region1;                         // 8 MB over eg(6)+Wp(3)
  bf16_t* prh = (bf16_t*)(region0 + 0 * 2097152);        // psi over weight splits
  bf16_t* prl = (bf16_t*)(region0 + 1 * 2097152);
  bf16_t* pih = (bf16_t*)(region0 + 2 * 2097152);
  bf16_t* pil = (bf16_t*)(region0 + 3 * 2097152);

  // zero initial h (h0_hi + h0_lo contiguous)
  hipMemsetAsync(h0_hi, 0, (size_t)B_ * E_ * 2 * 2, stream);

  // splits
  auto split = [&](const float* src, bf16_t* hi, bf16_t* lo, int n) {
    split4_kernel<<<(n / 4 + 255) / 256, 256, 0, stream>>>(src, hi, lo, n);
  };
  split(embed, emb_hi, emb_lo, V_ * E_);
  split(W_ih, wih_hi, wih_lo, G3_ * E_);
  split(Wc, wc_hi, wc_lo, M2_ * E_);
  split(R_real, rr_hi, rr_lo, V_ * M_);
  split(R_imag, ri_hi, ri_lo, V_ * M_);
  permute_whh_split<<<G3_, 256, 0, stream>>>(W_hh, Wp_hi, Wp_lo);

  // trig tables
  auto sc = [&](const float* x, float* c, float* s, int n) {
    sincos_kernel<<<(n + 255) / 256, 256, 0, stream>>>(x, c, s, n);
  };
  sc(phase, cph, sph, L_ * M_);
  sc(theta_e, ce, se, L_ * PE_);
  sc(phi_e, cpe, spe, L_ * PE_);
  sc(rho_e, cre, sre_, L_ * PE_);
  sc(theta_o, co, so, L_ * PO_);
  sc(phi_o, cpo, spo, L_ * PO_);
  sc(rho_o, cro, sro, L_ * PO_);

  // eg = embed @ W_ih^T   (V x 3E)
  {
    dim3 grid(G3_ / 64, V_ / 64);
    gemm_bt_mfma_split<<<grid, 256, 0, stream>>>(emb_hi, emb_lo, wih_hi, wih_lo,
                                                 eg, G3_, E_);
  }

  // GRU: 64 fused steps, ping-pong h buffers
  for (int t = 0; t < T_; ++t) {
    const bf16_t* ih = (t & 1) ? h1_hi : h0_hi;
    const bf16_t* il = (t & 1) ? h1_lo : h0_lo;
    bf16_t* oh = (t & 1) ? h0_hi : h1_hi;
    bf16_t* ol = (t & 1) ? h0_lo : h1_lo;
    dim3 grid(8, 16);
    gru_step<<<grid, 256, 0, stream>>>(ih, il, Wp_hi, Wp_lo, tokens, eg, b_ih,
                                       b_hh, oh, ol, t);
  }
  // final h is in buffer 0 (t=63 writes h0)
  // zc = h @ Wc^T  (B x 2M) -- overwrites eg/Wp region (dead)
  {
    dim3 grid(M2_ / 64, B_ / 64);
    gemm_bt_mfma_split<<<grid, 256, 0, stream>>>(h0_hi, h0_lo, wc_hi, wc_lo,
                                                 zc, M2_, E_);
  }

  // MZI stack -> psi hi/lo (overwrites weight-split region, dead)
  quantum_core<<<B_, 256, 0, stream>>>(zc, bc, cph, sph, ce, se, cpe, spe, cre,
                                       sre_, co, so, cpo, spo, cro, sro,
                                       prh, prl, pih, pil);

  // readout
  {
    dim3 grid(V_ / 64, B_ / 64);
    readout_mfma<<<grid, 256, 0, stream>>>(prh, prl, pih, pil, rr_hi, rr_lo,
                                           ri_hi, ri_lo, out);
  }

  // logsumexp
  lse_kernel<<<B_, 256, 0, stream>>>(out);
}